// Round 2
// baseline (205.814 us; speedup 1.0000x reference)
//
#include <hip/hip_runtime.h>
#include <hip/hip_bf16.h>
#include <math.h>

#define ROWS 256
#define DD 64
#define EE 8
#define HH 64
#define GHD 32

typedef __attribute__((ext_vector_type(8))) short bf16x8;
typedef __attribute__((ext_vector_type(4))) float f32x4;

static __device__ __forceinline__ short f2bf(float f) {
    unsigned u = __builtin_bit_cast(unsigned, f);
    unsigned r = (u + 0x7fffu + ((u >> 16) & 1u)) >> 16;  // round-to-nearest-even
    return (short)r;
}
// packed f32x2 -> bf16x2 (lowers to v_cvt_pk_bf16_f32, RNE — bit-identical to f2bf)
static __device__ __forceinline__ unsigned pk2(float lo, float hi) {
    __hip_bfloat162 h = __float22bfloat162_rn(make_float2(lo, hi));
    unsigned r;
    __builtin_memcpy(&r, &h, 4);
    return r;
}
// butterfly add via DPP (ctrl must be a compile-time constant)
template <int CTRL>
static __device__ __forceinline__ float dpp_add(float x) {
    int xi = __builtin_bit_cast(int, x);
    int yi = __builtin_amdgcn_update_dpp(0, xi, CTRL, 0xF, 0xF, true);
    return x + __builtin_bit_cast(float, yi);
}
// cross-lane add via ds_bpermute (addr = (lane^mask)<<2, precomputed)
static __device__ __forceinline__ float bperm_add(float x, int addr) {
    int xi = __builtin_bit_cast(int, x);
    int yi = __builtin_amdgcn_ds_bpermute(addr, xi);
    return x + __builtin_bit_cast(float, yi);
}

// Precompute W1 (experts) and gw1 (gating) as bf16 MFMA B-fragments in d_ws.
// expert frags: idx = wave<<10 | tt<<7 | half<<6 | lane, 8 shorts each (64 KB)
// gating frags: 2 tiles x 64 lanes x 8 shorts at short-offset 32768 (2 KB)
// d_ws must be >= 67584 bytes.
__global__ __launch_bounds__(256) void prep_kernel(const float* __restrict__ ew1,
                                                   const float* __restrict__ gw1,
                                                   short* __restrict__ wf) {
    int idx = blockIdx.x * 256 + threadIdx.x;   // 4096 frags
    int lane = idx & 63;
    int half = (idx >> 6) & 1;
    int tt   = (idx >> 7) & 7;
    int wave = (idx >> 10) & 3;
    int n = wave * 128 + tt * 16 + (lane & 15);
    int e = n >> 6, h = n & 63;
    int quad = lane >> 4;
    short v[8];
    #pragma unroll
    for (int j = 0; j < 8; ++j) {
        int dl = quad * 8 + j + half * 32;
        v[j] = f2bf(ew1[(e * DD + dl) * HH + h]);
    }
    *(bf16x8*)(wf + (size_t)idx * 8) = *(const bf16x8*)v;
    if (idx < 128) {                            // gw1 B-frags: B[k=d][col=g]
        int tile = idx >> 6;
        int lr = lane & 15;
        short g[8];
        #pragma unroll
        for (int j = 0; j < 8; ++j)
            g[j] = f2bf(gw1[(quad * 8 + j) * GHD + tile * 16 + lr]);
        *(bf16x8*)(wf + 32768 + (size_t)idx * 8) = *(const bf16x8*)g;
    }
}

__global__ __launch_bounds__(256, 3) void moe_kernel(
    const float* __restrict__ A, const float* __restrict__ S,
    const float* __restrict__ gb1, const float* __restrict__ gw2,
    const float* __restrict__ gb2, const short* __restrict__ wf,
    const float* __restrict__ eb1, const float* __restrict__ ew2,
    const float* __restrict__ eb2, float* __restrict__ out)
{
    // xs row = 72 shorts (144 B): [0..63] bf16 x-data, [64..71] = 4 f32 result slots (1/wave).
    __shared__ __align__(16) short xs[ROWS][72];     // 36864 B
    __shared__ __align__(16) float ps[ROWS][EE];     // 8192 B  (f32 gating probs)
    __shared__ __align__(16) float ghs[4][16][36];   // 9216 B  (per-wave gh transpose, pad 36 -> conflict-free)
    // total 54272 B -> 3 blocks/CU (= current effective occupancy)

    const int t = threadIdx.x;
    const int row0 = blockIdx.x * ROWS;
    const int lane = t & 63;
    const int wave = t >> 6;
    const int quad = lane >> 4;
    const int lr = lane & 15;

    // ---- Phase 1: x -> bf16 LDS (cvt_pk, 1 inst / 2 values) ----
    {
        const int row = row0 + t;
        const float4* ar = (const float4*)(A + (size_t)row * 32);
        const float4* sr = (const float4*)(S + (size_t)row * 32);
        #pragma unroll
        for (int i = 0; i < 4; ++i) {
            float4 v0 = ar[2 * i], v1 = ar[2 * i + 1];
            uint4 u;
            u.x = pk2(v0.x, v0.y); u.y = pk2(v0.z, v0.w);
            u.z = pk2(v1.x, v1.y); u.w = pk2(v1.z, v1.w);
            *(uint4*)&xs[t][i * 8] = u;
        }
        #pragma unroll
        for (int i = 0; i < 4; ++i) {
            float4 v0 = sr[2 * i], v1 = sr[2 * i + 1];
            uint4 u;
            u.x = pk2(v0.x, v0.y); u.y = pk2(v0.z, v0.w);
            u.z = pk2(v1.x, v1.y); u.w = pk2(v1.z, v1.w);
            *(uint4*)&xs[t][32 + i * 8] = u;
        }
    }
    // Wave-local ordering: this wave's 64 lanes wrote rows [wave*64, wave*64+64);
    // the gating phase below reads exactly those rows -> no __syncthreads needed,
    // but force the cross-lane LDS writes to drain before any read (rule #18).
    asm volatile("s_waitcnt lgkmcnt(0)" ::: "memory");
    __builtin_amdgcn_sched_barrier(0);

    // ---- Phase 1.5: gating on the matrix pipe (per wave, own 4 row-tiles) ----
    {
        const short* gwf = wf + 32768;
        bf16x8 gf0 = *(const bf16x8*)(gwf + (size_t)lane * 8);         // gw1 cols 0..15
        bf16x8 gf1 = *(const bf16x8*)(gwf + 512 + (size_t)lane * 8);   // gw1 cols 16..31
        float gw2r[8][8];                                              // this quad's g-slice of gw2
        #pragma unroll
        for (int j = 0; j < 8; ++j) {
            float4 a0 = *(const float4*)(gw2 + (quad * 8 + j) * 8);
            float4 a1 = *(const float4*)(gw2 + (quad * 8 + j) * 8 + 4);
            gw2r[j][0] = a0.x; gw2r[j][1] = a0.y; gw2r[j][2] = a0.z; gw2r[j][3] = a0.w;
            gw2r[j][4] = a1.x; gw2r[j][5] = a1.y; gw2r[j][6] = a1.z; gw2r[j][7] = a1.w;
        }
        const float gb1v0 = gb1[lr], gb1v1 = gb1[lr + 16];
        float gb2v[8];
        #pragma unroll
        for (int e = 0; e < 8; ++e) gb2v[e] = gb2[e];
        const int a16 = (lane ^ 16) << 2;
        const int a32 = (lane ^ 32) << 2;

        #pragma unroll 1
        for (int i = 0; i < 4; ++i) {
            const int rt = wave * 4 + i;
            // A-frag = S part of xs (k=0..31 of gw1 == S dims)
            bf16x8 sa = *(const bf16x8*)&xs[rt * 16 + lr][32 + quad * 8];
            f32x4 acc0 = {gb1v0, gb1v0, gb1v0, gb1v0};
            f32x4 acc1 = {gb1v1, gb1v1, gb1v1, gb1v1};
            acc0 = __builtin_amdgcn_mfma_f32_16x16x32_bf16(sa, gf0, acc0, 0, 0, 0);
            acc1 = __builtin_amdgcn_mfma_f32_16x16x32_bf16(sa, gf1, acc1, 0, 0, 0);
            // relu + transpose through LDS: C/D (lane=col) -> row-major gh
            #pragma unroll
            for (int r = 0; r < 4; ++r) {
                ghs[wave][quad * 4 + r][lr]      = fmaxf(acc0[r], 0.f);
                ghs[wave][quad * 4 + r][lr + 16] = fmaxf(acc1[r], 0.f);
            }
            asm volatile("s_waitcnt lgkmcnt(0)" ::: "memory");
            __builtin_amdgcn_sched_barrier(0);
            // lane: row = lr, g-slice = quad*8..+8 ; partial logits
            f32x4 g0 = *(const f32x4*)&ghs[wave][lr][quad * 8];
            f32x4 g1 = *(const f32x4*)&ghs[wave][lr][quad * 8 + 4];
            float lg[8];
            #pragma unroll
            for (int e = 0; e < 8; ++e) lg[e] = 0.f;
            #pragma unroll
            for (int j = 0; j < 4; ++j) {
                #pragma unroll
                for (int e = 0; e < 8; ++e) lg[e] = fmaf(g0[j], gw2r[j][e], lg[e]);
            }
            #pragma unroll
            for (int j = 0; j < 4; ++j) {
                #pragma unroll
                for (int e = 0; e < 8; ++e) lg[e] = fmaf(g1[j], gw2r[4 + j][e], lg[e]);
            }
            // reduce partials across the 4 lane-groups (xor16 then xor32)
            #pragma unroll
            for (int e = 0; e < 8; ++e) {
                float v = bperm_add(lg[e], a16);
                v = bperm_add(v, a32);
                lg[e] = v + gb2v[e];
            }
            // softmax (16 rows in parallel across lr lanes; quads redundant)
            float mx = fmaxf(fmaxf(fmaxf(lg[0], lg[1]), fmaxf(lg[2], lg[3])),
                             fmaxf(fmaxf(lg[4], lg[5]), fmaxf(lg[6], lg[7])));
            float pv[8], sum = 0.f;
            #pragma unroll
            for (int e = 0; e < 8; ++e) { pv[e] = __expf(lg[e] - mx); sum += pv[e]; }
            const float inv = __builtin_amdgcn_rcpf(sum);
            if (quad == 0) {
                float4 p0 = make_float4(pv[0] * inv, pv[1] * inv, pv[2] * inv, pv[3] * inv);
                float4 p1 = make_float4(pv[4] * inv, pv[5] * inv, pv[6] * inv, pv[7] * inv);
                *(float4*)&ps[rt * 16 + lr][0] = p0;
                *(float4*)&ps[rt * 16 + lr][4] = p1;
            }
        }
    }

    // ---- Load expert B fragments + per-column w2/b1 ----
    bf16x8 blo[8], bhi[8];
    float w2p[8], b1c[8];
    const int e0 = wave * 2;
    #pragma unroll
    for (int tt = 0; tt < 8; ++tt) {
        const short* base = wf + ((size_t)((wave * 8 + tt) * 128) + lane) * 8;
        blo[tt] = *(const bf16x8*)base;
        bhi[tt] = *(const bf16x8*)(base + 512);
        int n = wave * 128 + tt * 16 + lr;
        int e = n >> 6, h = n & 63;
        w2p[tt] = ew2[e * HH + h];
        b1c[tt] = eb1[e * HH + h];
    }
    const float ebi0 = eb2[e0] * 0.0625f;        // eb2 folded into per-lane partial init
    const float ebi1 = eb2[e0 + 1] * 0.0625f;    // (16 lanes sum to eb2[e])

    __syncthreads();

    // ---- Phase 2: expert MFMA over 16-row tiles ----
    #pragma unroll 1
    for (int rt = 0; rt < ROWS / 16; ++rt) {
        const short* xp = &xs[rt * 16 + lr][quad * 8];
        bf16x8 alo = *(const bf16x8*)xp;          // k in [0,32)
        bf16x8 ahi = *(const bf16x8*)(xp + 32);   // k in [32,64)
        f32x4 acc[8];
        #pragma unroll
        for (int tt = 0; tt < 8; ++tt)            // bias pre-loaded into accumulator
            acc[tt] = (f32x4){b1c[tt], b1c[tt], b1c[tt], b1c[tt]};
        #pragma unroll
        for (int tt = 0; tt < 8; ++tt)
            acc[tt] = __builtin_amdgcn_mfma_f32_16x16x32_bf16(alo, blo[tt], acc[tt], 0, 0, 0);
        #pragma unroll
        for (int tt = 0; tt < 8; ++tt)
            acc[tt] = __builtin_amdgcn_mfma_f32_16x16x32_bf16(ahi, bhi[tt], acc[tt], 0, 0, 0);

        // epilogue: relu, fold w2, per-expert partials (4 tiles each)
        float pe0[4] = {ebi0, ebi0, ebi0, ebi0};
        float pe1[4] = {ebi1, ebi1, ebi1, ebi1};
        #pragma unroll
        for (int tt = 0; tt < 8; ++tt) {
            #pragma unroll
            for (int r = 0; r < 4; ++r) {
                float v = fmaxf(acc[tt][r], 0.0f);
                if (tt < 4) pe0[r] = fmaf(v, w2p[tt], pe0[r]);
                else        pe1[r] = fmaf(v, w2p[tt], pe1[r]);
            }
        }
        #pragma unroll
        for (int r = 0; r < 4; ++r) {
            const int rw = rt * 16 + quad * 4 + r;   // C/D row = quad*4+reg
            float c = fmaf(pe0[r], ps[rw][e0], pe1[r] * ps[rw][e0 + 1]);
            c = dpp_add<0xB1>(c);                 // quad_perm xor 1
            c = dpp_add<0x4E>(c);                 // quad_perm xor 2
            c = dpp_add<0x124>(c);                // row_ror:4
            c = dpp_add<0x128>(c);                // row_ror:8
            if (lr == 0) *(float*)&xs[rw][64 + 2 * wave] = c;   // private slot, no atomic
        }
    }

    __syncthreads();
    const float4 fs = *(const float4*)&xs[t][64];
    out[row0 + t] = (fs.x + fs.y) + (fs.z + fs.w);
}

extern "C" void kernel_launch(void* const* d_in, const int* in_sizes, int n_in,
                              void* d_out, int out_size, void* d_ws, size_t ws_size,
                              hipStream_t stream) {
    const float* A   = (const float*)d_in[0];
    const float* S   = (const float*)d_in[1];
    const float* gw1 = (const float*)d_in[2];
    const float* gb1 = (const float*)d_in[3];
    const float* gw2 = (const float*)d_in[4];
    const float* gb2 = (const float*)d_in[5];
    const float* ew1 = (const float*)d_in[6];
    const float* eb1 = (const float*)d_in[7];
    const float* ew2 = (const float*)d_in[8];
    const float* eb2 = (const float*)d_in[9];
    float* out = (float*)d_out;
    short* wf = (short*)d_ws;   // 64 KB expert W1 frags + 2 KB gating gw1 frags

    const int B = in_sizes[0] / 32;
    hipLaunchKernelGGL(prep_kernel, dim3(16), dim3(256), 0, stream, ew1, gw1, wf);
    hipLaunchKernelGGL(moe_kernel, dim3(B / ROWS), dim3(256), 0, stream,
                       A, S, gb1, gw2, gb2, wf, eb1, ew2, eb2, out);
}